// Round 15
// baseline (173.437 us; speedup 1.0000x reference)
//
#include <hip/hip_runtime.h>
#include <math.h>

// Problem constants
constexpr int B = 16, S = 100, T = 60, D = 512, H = 8, V = 32000, R = 20;
constexpr int DK = 64, WIN = 20;
constexpr int VR = V + R;        // 32020
constexpr int BT = B * T;        // 960
constexpr int MP = 1024;         // padded GEMM M
constexpr int FP = 384;          // padded B*R rows for kh GEMM
constexpr int VBP = 1664;        // padded B*S rows for vWqr GEMM (13*128)

typedef unsigned short u16;
typedef __attribute__((ext_vector_type(8))) short bf16x8;
typedef __attribute__((ext_vector_type(4))) float f32x4;

__device__ __forceinline__ float wred_sum(float v) {
#pragma unroll
  for (int st = 32; st > 0; st >>= 1) v += __shfl_xor(v, st, 64);
  return v;
}
__device__ __forceinline__ float wred_max(float v) {
#pragma unroll
  for (int st = 32; st > 0; st >>= 1) v = fmaxf(v, __shfl_xor(v, st, 64));
  return v;
}
__device__ __forceinline__ float sigmoidf_(float x) { return 1.f / (1.f + expf(-x)); }
__device__ __forceinline__ u16 f2bf(float x) {
  unsigned u = __float_as_uint(x);
  return (u16)((u + 0x7fffu + ((u >> 16) & 1u)) >> 16);
}
__device__ __forceinline__ void gload_lds16(const u16* g, u16* l) {
  __builtin_amdgcn_global_load_lds((const __attribute__((address_space(1))) void*)g,
                                   (__attribute__((address_space(3))) void*)l, 16, 0, 0);
}

// ================= bodies =================

__device__ __forceinline__ void vn_body(int row, int l, const float* __restrict__ v,
                                        const float* __restrict__ Wn,
                                        float* __restrict__ vn, float* __restrict__ vn2) {
  const float* vr = v + (size_t)row * D + l * 8;
  float p0 = 0.f, p1 = 0.f;
#pragma unroll
  for (int i = 0; i < 8; i++) {
    float x = vr[i];
    p0 = fmaf(x, Wn[l * 8 + i], p0);
    p1 = fmaf(x, Wn[D + l * 8 + i], p1);
  }
  p0 = wred_sum(p0); p1 = wred_sum(p1);
  if (l == 0) { vn[row] = p0; vn2[row] = p1; }
}

__device__ __forceinline__ void attnscal_body(int row, int l,
    const float* __restrict__ logits, const float* __restrict__ q,
    const float* __restrict__ Wr, const float* __restrict__ br,
    const float* __restrict__ Wa, const float* __restrict__ ba,
    const float* __restrict__ Wptr, const float* __restrict__ bptr,
    float* __restrict__ attn_g, float* __restrict__ remv,
    float* __restrict__ addp, float* __restrict__ pgen) {
  const float* src = logits + (size_t)row * S;
  float a = src[l];
  float b2 = (l + 64 < S) ? src[l + 64] : -INFINITY;
  float m = wred_max(fmaxf(a, b2));
  float ea = expf(a - m), eb = (l + 64 < S) ? expf(b2 - m) : 0.f;
  float inv = 1.f / wred_sum(ea + eb);
  attn_g[(size_t)row * S + l] = ea * inv;
  if (l + 64 < S) attn_g[(size_t)row * S + l + 64] = eb * inv;

  const float* qr = q + (size_t)row * D + l * 8;
  float pr = 0.f, pa = 0.f, pp = 0.f;
#pragma unroll
  for (int i = 0; i < 8; i++) {
    float x = qr[i];
    pr = fmaf(x, Wr[l * 8 + i], pr);
    pa = fmaf(x, Wa[l * 8 + i], pa);
    pp = fmaf(x, Wptr[l * 8 + i], pp);
  }
#pragma unroll
  for (int st = 32; st > 0; st >>= 1) {
    pr += __shfl_xor(pr, st, 64);
    pa += __shfl_xor(pa, st, 64);
    pp += __shfl_xor(pp, st, 64);
  }
  if (l == 0) {
    remv[row] = sigmoidf_(pr + br[0]);
    addp[row] = sigmoidf_(pa + ba[0]);
    pgen[row] = sigmoidf_(pp + bptr[0]);
  }
}

__device__ __forceinline__ void attnw_body(int row, int tid, float* red,
    const float* __restrict__ attn, const float* __restrict__ vn2,
    const float* __restrict__ remv, float* __restrict__ ra, float* __restrict__ ctxn) {
  int b = row / T, t = row % T;
  int L = min(t + 1, WIN);
  if (tid < 128) {
    float dnm = 0.f;
    for (int j = 0; j < L; j++) dnm += expf((float)(WIN - j) / 20.f);
    float p = 0.f;
    if (tid < S) {
      float aw = 0.f;
      for (int j = 0; j < L; j++)
        aw = fmaf(expf((float)(WIN - j) / 20.f) / dnm, attn[(size_t)(row - j) * S + tid], aw);
      ra[(size_t)row * S + tid] = remv[row] * aw;
      p = aw * vn2[b * S + tid];
    }
    red[tid] = p;
  }
  __syncthreads();
  if (tid < 64) {
    float v2 = red[tid] + red[tid + 64];
    v2 = wred_sum(v2);
    if (tid == 0) ctxn[row] = v2;
  }
}

// ---- prep (conversions incl Wlogit & v->bf16, qw window, weight transposes) ----
constexpr int NW = V * D / 4;                      // 4,096,000
constexpr int NQ = MP * D / 4;                     // 131,072
constexpr int NWQ = D * D / 4;                     // 65,536
constexpr int NF = FP * D / 4;                     // 49,152
constexpr int NVB = VBP * D / 4;                   // 212,992
constexpr int NB_CVT = (NW + NQ + NWQ + NF + NVB) / 256;  // 17792 exact
constexpr int NB_QWB = MP;
constexpr int NB_PREP = NB_CVT + NB_QWB + 128;     // 18944
__device__ __forceinline__ void prep_body(int blk, int tid, float (*tile)[65],
    const float* __restrict__ Wlogit, const float* __restrict__ q,
    const float* __restrict__ Wq, const float* __restrict__ f, const float* __restrict__ v,
    const float* __restrict__ Wqr, const float* __restrict__ Wkr,
    u16* __restrict__ Wlbf, u16* __restrict__ qbf,
    u16* __restrict__ Wqlb, u16* __restrict__ fb, u16* __restrict__ vb,
    u16* __restrict__ qwb, u16* __restrict__ WqrT, u16* __restrict__ WkrT) {
  if (blk < NB_CVT) {
    int idx = blk * 256 + tid;
    if (idx < NW) {
      float4 x = reinterpret_cast<const float4*>(Wlogit)[idx];
      ushort4 o = {f2bf(x.x), f2bf(x.y), f2bf(x.z), f2bf(x.w)};
      reinterpret_cast<ushort4*>(Wlbf)[idx] = o;
    } else if (idx < NW + NQ) {
      int j = idx - NW;
      int row = (j * 4) / D;
      ushort4 o = {0, 0, 0, 0};
      if (row < BT) {
        float4 x = reinterpret_cast<const float4*>(q)[j];
        o = {f2bf(x.x), f2bf(x.y), f2bf(x.z), f2bf(x.w)};
      }
      reinterpret_cast<ushort4*>(qbf)[j] = o;
    } else if (idx < NW + NQ + NWQ) {
      int j = idx - NW - NQ;
      float4 x = reinterpret_cast<const float4*>(Wq)[j];
      ushort4 o = {f2bf(x.x), f2bf(x.y), f2bf(x.z), f2bf(x.w)};
      reinterpret_cast<ushort4*>(Wqlb)[j] = o;
    } else if (idx < NW + NQ + NWQ + NF) {
      int j = idx - NW - NQ - NWQ;
      int row = (j * 4) / D;
      ushort4 o = {0, 0, 0, 0};
      if (row < B * R) {
        float4 x = reinterpret_cast<const float4*>(f)[j];
        o = {f2bf(x.x), f2bf(x.y), f2bf(x.z), f2bf(x.w)};
      }
      reinterpret_cast<ushort4*>(fb)[j] = o;
    } else {
      int j = idx - NW - NQ - NWQ - NF;            // 0 .. NVB-1
      int row = (j * 4) / D;
      ushort4 o = {0, 0, 0, 0};
      if (row < B * S) {
        float4 x = reinterpret_cast<const float4*>(v)[j];
        o = {f2bf(x.x), f2bf(x.y), f2bf(x.z), f2bf(x.w)};
      }
      reinterpret_cast<ushort4*>(vb)[j] = o;
    }
  } else if (blk < NB_CVT + NB_QWB) {
    int row = blk - NB_CVT;
    if (row >= BT) {
      qwb[(size_t)row * D + tid] = 0; qwb[(size_t)row * D + tid + 256] = 0;
      return;
    }
    int t = row % T, L = min(t + 1, WIN);
    float dnm = 0.f;
    for (int j = 0; j < L; j++) dnm += expf((float)(WIN - j) / 20.f);
    float a0 = 0.f, a1 = 0.f;
    for (int j = 0; j < L; j++) {
      float wj = expf((float)(WIN - j) / 20.f) / dnm;
      a0 = fmaf(wj, q[(size_t)(row - j) * D + tid], a0);
      a1 = fmaf(wj, q[(size_t)(row - j) * D + tid + 256], a1);
    }
    qwb[(size_t)row * D + tid] = f2bf(a0);
    qwb[(size_t)row * D + tid + 256] = f2bf(a1);
  } else {
    int qt = blk - NB_CVT - NB_QWB;                // 0..127
    const float* src = (qt < 64) ? Wqr : Wkr;
    u16* dst = (qt < 64) ? WqrT : WkrT;
    int q64 = qt & 63;
    int bx = q64 % 8, by = q64 / 8;
#pragma unroll
    for (int i = 0; i < 16; i++) {
      int e = i * 256 + tid, r = e >> 6, c = e & 63;
      tile[r][c] = src[(size_t)(by * 64 + r) * D + bx * 64 + c];
    }
    __syncthreads();
#pragma unroll
    for (int i = 0; i < 16; i++) {
      int e = i * 256 + tid, r = e >> 6, c = e & 63;
      dst[(size_t)(bx * 64 + r) * D + by * 64 + c] = f2bf(tile[c][r]);
    }
  }
}

__device__ __forceinline__ void gemm512_body(const u16* __restrict__ A, const u16* __restrict__ Bw,
                                             const float* __restrict__ bias, float* __restrict__ outp,
                                             int mlimit, int mt, int nt, int tid, u16* ldsbuf) {
  u16* As = ldsbuf;
  u16* Bs = ldsbuf + 128 * 64;
  int m0 = mt * 128, n0 = nt * 128;
  int l = tid & 63;
  int w = tid >> 6, wm = w >> 1, wn = w & 1;
  f32x4 acc[4][4];
#pragma unroll
  for (int mb = 0; mb < 4; mb++)
#pragma unroll
    for (int nb = 0; nb < 4; nb++) acc[mb][nb] = (f32x4){0.f, 0.f, 0.f, 0.f};

  for (int k0 = 0; k0 < D; k0 += 64) {
#pragma unroll
    for (int i = 0; i < 4; i++) {
      int chunk = i * 256 + tid;
      int row = chunk >> 3, kc = chunk & 7;
      int kcs = kc ^ (row & 7);
      gload_lds16(A + (size_t)(m0 + row) * D + k0 + kcs * 8, As + chunk * 8);
      gload_lds16(Bw + (size_t)(n0 + row) * D + k0 + kcs * 8, Bs + chunk * 8);
    }
    __syncthreads();
#pragma unroll
    for (int kk = 0; kk < 2; kk++) {
      bf16x8 af[4], bfr[4];
#pragma unroll
      for (int mb = 0; mb < 4; mb++) {
        int row = wm * 64 + mb * 16 + (l & 15);
        int kc0 = kk * 4 + (l >> 4);
        af[mb] = *(const bf16x8*)(As + row * 64 + ((kc0 ^ (row & 7)) << 3));
      }
#pragma unroll
      for (int nb = 0; nb < 4; nb++) {
        int row = wn * 64 + nb * 16 + (l & 15);
        int kc0 = kk * 4 + (l >> 4);
        bfr[nb] = *(const bf16x8*)(Bs + row * 64 + ((kc0 ^ (row & 7)) << 3));
      }
#pragma unroll
      for (int mb = 0; mb < 4; mb++)
#pragma unroll
        for (int nb = 0; nb < 4; nb++)
          acc[mb][nb] = __builtin_amdgcn_mfma_f32_16x16x32_bf16(af[mb], bfr[nb], acc[mb][nb], 0, 0, 0);
    }
    __syncthreads();
  }

  float* ch = (float*)ldsbuf;
#pragma unroll
  for (int c = 0; c < 4; c++) {
    if (wm == (c >> 1)) {
#pragma unroll
      for (int nb = 0; nb < 4; nb++) {
        int col = wn * 64 + nb * 16 + (l & 15);
        float bl = bias ? bias[n0 + col] : 0.f;
#pragma unroll
        for (int mbi = 0; mbi < 2; mbi++) {
          int mb = (c & 1) * 2 + mbi;
#pragma unroll
          for (int q2 = 0; q2 < 4; q2++) {
            int row_local = mb * 16 + (l >> 4) * 4 + q2 - (c & 1) * 32;
            ch[row_local * 132 + col] = acc[mb][nb][q2] + bl;
          }
        }
      }
    }
    __syncthreads();
#pragma unroll
    for (int p = 0; p < 4; p++) {
      int r = p * 8 + (tid >> 5);
      int m = m0 + c * 32 + r;
      if (m < mlimit) {
        int seg = tid & 31;
        *(float4*)(outp + (size_t)m * D + n0 + seg * 4) =
            *(const float4*)(ch + r * 132 + seg * 4);
      }
    }
    __syncthreads();
  }
}

__device__ __forceinline__ void vocab_body(int bid, int tid, u16* ldsbuf,
    const u16* __restrict__ A, const u16* __restrict__ Bw,
    const float* __restrict__ blog, float* __restrict__ out) {
  u16* As = ldsbuf;
  u16* Bs = ldsbuf + 128 * 64;
  int swz = (bid & 7) * 250 + (bid >> 3);          // bijective on [0,2000)
  int m0 = (swz & 7) * 128, n0 = (swz >> 3) * 128;
  int l = tid & 63;
  int w = tid >> 6, wm = w >> 1, wn = w & 1;

  f32x4 acc[4][4];
#pragma unroll
  for (int mb = 0; mb < 4; mb++)
#pragma unroll
    for (int nb = 0; nb < 4; nb++) acc[mb][nb] = (f32x4){0.f, 0.f, 0.f, 0.f};

  for (int k0 = 0; k0 < D; k0 += 64) {
#pragma unroll
    for (int i = 0; i < 4; i++) {
      int chunk = i * 256 + tid;
      int row = chunk >> 3, kc = chunk & 7;
      int kcs = kc ^ (row & 7);
      gload_lds16(A + (size_t)(m0 + row) * D + k0 + kcs * 8, As + chunk * 8);
      gload_lds16(Bw + (size_t)(n0 + row) * D + k0 + kcs * 8, Bs + chunk * 8);
    }
    __syncthreads();
#pragma unroll
    for (int kk = 0; kk < 2; kk++) {
      bf16x8 af[4], bfr[4];
#pragma unroll
      for (int mb = 0; mb < 4; mb++) {
        int row = wm * 64 + mb * 16 + (l & 15);
        int kc0 = kk * 4 + (l >> 4);
        af[mb] = *(const bf16x8*)(As + row * 64 + ((kc0 ^ (row & 7)) << 3));
      }
#pragma unroll
      for (int nb = 0; nb < 4; nb++) {
        int row = wn * 64 + nb * 16 + (l & 15);
        int kc0 = kk * 4 + (l >> 4);
        bfr[nb] = *(const bf16x8*)(Bs + row * 64 + ((kc0 ^ (row & 7)) << 3));
      }
#pragma unroll
      for (int mb = 0; mb < 4; mb++)
#pragma unroll
        for (int nb = 0; nb < 4; nb++)
          acc[mb][nb] = __builtin_amdgcn_mfma_f32_16x16x32_bf16(af[mb], bfr[nb], acc[mb][nb], 0, 0, 0);
    }
    __syncthreads();
  }

  float* ch = (float*)ldsbuf;
#pragma unroll
  for (int c = 0; c < 4; c++) {
    if (wm == (c >> 1)) {
#pragma unroll
      for (int nb = 0; nb < 4; nb++) {
        int col = wn * 64 + nb * 16 + (l & 15);
        float bl = blog[n0 + col];
#pragma unroll
        for (int mbi = 0; mbi < 2; mbi++) {
          int mb = (c & 1) * 2 + mbi;
#pragma unroll
          for (int q2 = 0; q2 < 4; q2++) {
            int row_local = mb * 16 + (l >> 4) * 4 + q2 - (c & 1) * 32;
            ch[row_local * 132 + col] = acc[mb][nb][q2] + bl;
          }
        }
      }
    }
    __syncthreads();
#pragma unroll
    for (int p = 0; p < 4; p++) {
      int r = p * 8 + (tid >> 5);
      int m = m0 + c * 32 + r;
      if (m < BT) {
        int seg = tid & 31;
        *(float4*)(out + (size_t)m * VR + n0 + seg * 4) =
            *(const float4*)(ch + r * 132 + seg * 4);
      }
    }
    __syncthreads();
  }
}

// ---- M[b,h,r,s] = sum_dk vWqr[b,s,h*64+dk]*khf[b,r,h*64+dk]; slot s=100 holds bias term ----
__device__ __forceinline__ void mrole_body(int bh, int tid, float* sm,
    const float* __restrict__ vWqr, const float* __restrict__ khf,
    const float* __restrict__ bqr, float* __restrict__ M) {
  int b = bh >> 3, h = bh & 7;
  float* kh_s = sm;              // [20][64]
  float* vW_s = sm + 1280;       // [100][64]
  float* bq_s = sm + 7680;       // [64]
#pragma unroll
  for (int ii = 0; ii < 2; ii++) {
    int i = ii * 256 + tid;
    if (i < 320) {                                 // 20*16 float4
      int r = i >> 4, c4 = (i & 15) * 4;
      *(float4*)&kh_s[r * 64 + c4] =
          *(const float4*)&khf[(size_t)(b * R + r) * D + h * 64 + c4];
    }
  }
#pragma unroll
  for (int ii = 0; ii < 7; ii++) {
    int i = ii * 256 + tid;
    if (i < 1600) {                                // 100*16 float4
      int s = i >> 4, c4 = (i & 15) * 4;
      *(float4*)&vW_s[s * 64 + c4] =
          *(const float4*)&vWqr[(size_t)(b * S + s) * D + h * 64 + c4];
    }
  }
  if (tid < 64) bq_s[tid] = bqr[h * 64 + tid];
  __syncthreads();
  for (int p = tid; p < R * 104; p += 256) {
    int r = p / 104, sc = p % 104;
    if (sc > 100) continue;
    const float* kp = kh_s + r * 64;
    const float* xp = (sc < 100) ? (vW_s + sc * 64) : bq_s;
    float acc = 0.f;
#pragma unroll
    for (int e = 0; e < 64; e += 4) {
      float4 x = *(const float4*)&xp[e];
      float4 k = *(const float4*)&kp[e];
      acc = fmaf(x.x, k.x, fmaf(x.y, k.y, fmaf(x.z, k.z, fmaf(x.w, k.w, acc))));
    }
    M[(size_t)(bh * R + r) * 104 + sc] = acc;
  }
}

// ---- vubeta: K-chunks of 128, float4 staged; emits gamma in t-major layout ----
__device__ __forceinline__ void vubeta_body(int bq, int tid, float* sm,
    const float* __restrict__ u, const float* __restrict__ v,
    const float* __restrict__ attn, const float* __restrict__ ra,
    const float* __restrict__ addp, const float* __restrict__ ctxn,
    const float* __restrict__ vn, const float* __restrict__ bn,
    float* __restrict__ gammaTt) {
  int b = bq / 5, sc = bq % 5;
  int tq = tid >> 2, sg = tid & 3;
  float* u_s = sm;               // [60][132]
  float* v_s = sm + 7920;        // [20][132]
  float* aw_s = sm + 10560;      // [60][20]
  float* ra_s = sm + 11760;
  float* vu_s = sm + 12960;
  float* gm_s = sm + 14160;
  float* ap_s = sm + 15360;
  float* cx_s = sm + 15420;
  float* vns_s = sm + 15480;
#pragma unroll
  for (int ii = 0; ii < 5; ii++) {
    int i = ii * 256 + tid;
    if (i < T * 20) {
      int t = i / 20, sl = i % 20;
      size_t base = ((size_t)b * T + t) * S + sc * 20 + sl;
      aw_s[t * 20 + sl] = attn[base];
      ra_s[t * 20 + sl] = ra[base];
    }
  }
  if (tid < T) { ap_s[tid] = addp[b * T + tid]; cx_s[tid] = ctxn[b * T + tid]; }
  if (tid >= 64 && tid < 84) vns_s[tid - 64] = vn[b * S + sc * 20 + tid - 64];

  float acc[5] = {0, 0, 0, 0, 0};
  for (int kc = 0; kc < 4; kc++) {                 // 128-wide K chunks
#pragma unroll
    for (int ii = 0; ii < 8; ii++) {
      int i = ii * 256 + tid;
      if (i < 60 * 32) {
        int r = i >> 5, c = (i & 31) * 4;
        *(float4*)&u_s[r * 132 + c] =
            *(const float4*)&u[((size_t)b * T + r) * D + kc * 128 + c];
      }
    }
#pragma unroll
    for (int ii = 0; ii < 3; ii++) {
      int i = ii * 256 + tid;
      if (i < 20 * 32) {
        int r = i >> 5, c = (i & 31) * 4;
        *(float4*)&v_s[r * 132 + c] =
            *(const float4*)&v[((size_t)b * S + sc * 20 + r) * D + kc * 128 + c];
      }
    }
    __syncthreads();
    if (tq < 60) {
#pragma unroll
      for (int e0 = 0; e0 < 128; e0 += 4) {
        float4 uu = *(const float4*)&u_s[tq * 132 + e0];
#pragma unroll
        for (int m = 0; m < 5; m++) {
          float4 vv = *(const float4*)&v_s[(sg * 5 + m) * 132 + e0];
          acc[m] = fmaf(uu.x, vv.x, acc[m]);
          acc[m] = fmaf(uu.y, vv.y, acc[m]);
          acc[m] = fmaf(uu.z, vv.z, acc[m]);
          acc[m] = fmaf(uu.w, vv.w, acc[m]);
        }
      }
    }
    __syncthreads();
  }
  if (tq < 60) {
#pragma unroll
    for (int m = 0; m < 5; m++) vu_s[tq * 20 + sg * 5 + m] = acc[m];
  }
  __syncthreads();
  if (tid < 20) {
    int s = sc * 20 + tid;
    float dec = (s < 50) ? 1.f - (float)(s + 1) / 50.f : 0.f;
    float a = dec, beta = dec;
    float vns = vns_s[tid], bnv = bn[0];
    for (int t = 0; t < T; t++) {
      float g = ap_s[t] * sigmoidf_(vns + cx_s[t] + bnv);
      float wv = (1.f - a) * g;
      a += wv;
      gm_s[t * 20 + tid] = aw_s[t * 20 + tid] * beta;   // gamma uses PRE-update beta
      beta = beta * (1.f - ra_s[t * 20 + tid] * sigmoidf_(beta * vu_s[t * 20 + tid])) + wv;
    }
  }
  __syncthreads();
  // t-major gamma: gammaTt[(b*T+t)*S + sc*20 + sl]
#pragma unroll
  for (int ii = 0; ii < 5; ii++) {
    int i = ii * 256 + tid;
    if (i < T * 20) {
      int t = i / 20, sl = i % 20;
      gammaTt[((size_t)b * T + t) * S + sc * 20 + sl] = gm_s[t * 20 + sl];
    }
  }
}

// ---- role from gamma·M (qh eliminated) ----
__device__ __forceinline__ void role_body(int row, int tid, float* sm,
    const float* __restrict__ M, const float* __restrict__ gammaTt,
    const float* __restrict__ pgen, float* __restrict__ out) {
  int b = row / T;
  float* gs = sm;                // [100]
  float* sc = sm + 104;          // [160]
  float* pr = sm + 264;          // [160]
  if (tid < S) gs[tid] = gammaTt[(size_t)row * S + tid];
  __syncthreads();
  if (tid < H * R) {
    int h = tid / R, r = tid % R;
    const float* mp = M + (size_t)((b * H + h) * R + r) * 104;
    float acc = mp[100];                           // folded bqr·kh bias term
    for (int s = 0; s < S; s++) acc = fmaf(gs[s], mp[s], acc);
    sc[tid] = acc * 0.125f;                        // 1/sqrt(64)
  }
  __syncthreads();
  if (tid < H) {
    float m = -INFINITY;
    for (int r = 0; r < R; r++) m = fmaxf(m, sc[tid * R + r]);
    float ssum = 0.f;
    for (int r = 0; r < R; r++) { float e = expf(sc[tid * R + r] - m); pr[tid * R + r] = e; ssum += e; }
    float inv = 1.f / ssum;
    for (int r = 0; r < R; r++) pr[tid * R + r] *= inv;
  }
  __syncthreads();
  if (tid < R) {
    float acc = 0.f;
#pragma unroll
    for (int h = 0; h < H; h++) acc += pr[h * R + tid];
    out[(size_t)row * VR + V + tid] = acc * (1.f / H) * pgen[row];
  }
}

// ================= dispatch kernels =================

// L1: prep (incl Wlogit/v cvt) + vn + attnscal — all input-only
__global__ __launch_bounds__(256) void k_combo1(
    const float* Wlogit, const float* q, const float* Wq, const float* f,
    const float* Wqr, const float* Wkr, const float* logits, const float* v,
    const float* Wn, const float* Wr, const float* br, const float* Wa, const float* ba,
    const float* Wptr, const float* bptr,
    u16* Wlbf, u16* qbf, u16* Wqlb, u16* fb, u16* vb, u16* qwb, u16* WqrT, u16* WkrT,
    float* vn, float* vn2, float* attn_g, float* remv, float* addp, float* pgen) {
  __shared__ float tile[64][65];
  int blk = blockIdx.x, tid = threadIdx.x;
  if (blk < NB_PREP) {
    prep_body(blk, tid, tile, Wlogit, q, Wq, f, v, Wqr, Wkr,
              Wlbf, qbf, Wqlb, fb, vb, qwb, WqrT, WkrT);
  } else if (blk < NB_PREP + 400) {
    int row = (blk - NB_PREP) * 4 + (tid >> 6);    // 1600 rows
    vn_body(row, tid & 63, v, Wn, vn, vn2);
  } else {
    int row = (blk - NB_PREP - 400) * 4 + (tid >> 6);  // 960 rows
    attnscal_body(row, tid & 63, logits, q, Wr, br, Wa, ba, Wptr, bptr,
                  attn_g, remv, addp, pgen);
  }
}

// L2: vocab [0,600) + dual gemm (44) + vWqr gemm (52) + attnw (960)
__global__ __launch_bounds__(256) void k_combo2(
    const u16* qbf, const u16* Wlbf, const float* blog, float* out,
    const u16* qwb, const u16* Wqlb, float* u,
    const u16* fb, const u16* WkrT, const float* bkr, float* khf,
    const u16* vb, const u16* WqrT, float* vWqr,
    const float* attn, const float* vn2, const float* remv, float* ra, float* ctxn) {
  __shared__ u16 lds[2 * 128 * 64];
  int blk = blockIdx.x, tid = threadIdx.x;
  if (blk < 600) {
    vocab_body(blk, tid, lds, qbf, Wlbf, blog, out);
  } else if (blk < 644) {
    int z = blk - 600, xx = z % 11, yy = z / 11;
    if (xx < 8) gemm512_body(qwb, Wqlb, nullptr, u, BT, xx, yy, tid, lds);
    else        gemm512_body(fb, WkrT, bkr, khf, B * R, xx - 8, yy, tid, lds);
  } else if (blk < 696) {
    int z = blk - 644;                             // 52 blocks: 13 x 4
    gemm512_body(vb, WqrT, nullptr, vWqr, B * S, z % 13, z / 13, tid, lds);
  } else {
    attnw_body(blk - 696, tid, (float*)lds, attn, vn2, remv, ra, ctxn);
  }
}

// L3: vubeta (80) + M-compute (128) + vocab [600,1200)
__global__ __launch_bounds__(256) void k_combo3(
    const float* u, const float* v, const float* attn, const float* ra,
    const float* addp, const float* ctxn, const float* vn, const float* bn,
    float* gammaTt,
    const float* vWqr, const float* khf, const float* bqr, float* M,
    const u16* qbf, const u16* Wlbf, const float* blog, float* out) {
  __shared__ float smem[15500];                    // 62 KB max (vubeta)
  int blk = blockIdx.x, tid = threadIdx.x;
  if (blk < 80)       vubeta_body(blk, tid, smem, u, v, attn, ra, addp, ctxn, vn, bn, gammaTt);
  else if (blk < 208) mrole_body(blk - 80, tid, smem, vWqr, khf, bqr, M);
  else                vocab_body(600 + blk - 208, tid, (u16*)smem, qbf, Wlbf, blog, out);
}

// L4: vocab [1200,2000) + role (960)
__global__ __launch_bounds__(256) void k_rolep(
    const float* M, const float* gammaTt, const float* pgen, float* out,
    const u16* qbf, const u16* Wlbf, const float* blog) {
  __shared__ u16 lds[2 * 128 * 64];
  int blk = blockIdx.x, tid = threadIdx.x;
  if (blk < 800) vocab_body(1200 + blk, tid, lds, qbf, Wlbf, blog, out);
  else           role_body(blk - 800, tid, (float*)lds, M, gammaTt, pgen, out);
}

extern "C" void kernel_launch(void* const* d_in, const int* in_sizes, int n_in,
                              void* d_out, int out_size, void* d_ws, size_t ws_size,
                              hipStream_t stream) {
  const float* v_out  = (const float*)d_in[0];
  const float* f_out  = (const float*)d_in[1];
  const float* q_seq  = (const float*)d_in[2];
  const float* logits = (const float*)d_in[3];
  const float* Wr     = (const float*)d_in[4];
  const float* br     = (const float*)d_in[5];
  const float* Wa     = (const float*)d_in[6];
  const float* ba     = (const float*)d_in[7];
  const float* Wq_lin = (const float*)d_in[8];
  const float* Wn     = (const float*)d_in[9];
  const float* bn     = (const float*)d_in[10];
  const float* Wlogit = (const float*)d_in[11];
  const float* blogit = (const float*)d_in[12];
  const float* Wptr   = (const float*)d_in[13];
  const float* bptr   = (const float*)d_in[14];
  const float* Wqr    = (const float*)d_in[15];
  const float* bqr    = (const float*)d_in[16];
  const float* Wkr    = (const float*)d_in[17];
  const float* bkr    = (const float*)d_in[18];
  float* out = (float*)d_out;
  float* ws  = (float*)d_ws;

  float* attn   = ws;                                  // BT*S
  float* ra     = attn   + (size_t)BT * S;             // BT*S
  float* u      = ra     + (size_t)BT * S;             // BT*D
  float* pgen   = u      + (size_t)BT * D;             // BT
  float* remv   = pgen   + BT;                         // BT
  float* addp   = remv   + BT;                         // BT
  float* ctxn   = addp   + BT;                         // BT
  float* vn     = ctxn   + BT;                         // B*S
  float* vn2    = vn     + B * S;                      // B*S
  float* khf    = vn2    + B * S;                      // B*R*D
  float* gammaTt= khf    + (size_t)B * R * D;          // BT*S
  float* M      = gammaTt+ (size_t)BT * S;             // B*H*R*104
  float* vWqr   = M      + (size_t)B * H * R * 104;    // B*S*D
  u16*   qwb    = (u16*)(vWqr + (size_t)B * S * D);    // MP*D
  u16*   vb     = qwb  + (size_t)MP * D;               // VBP*D
  u16*   fb     = vb   + (size_t)VBP * D;              // FP*D
  u16*   Wqlb   = fb   + (size_t)FP * D;               // D*D
  u16*   WqrT   = Wqlb + (size_t)D * D;                // D*D
  u16*   WkrT   = WqrT + (size_t)D * D;                // D*D
  u16*   qbf    = WkrT + (size_t)D * D;                // MP*D
  u16*   Wlbf   = qbf  + (size_t)MP * D;               // V*D

  // L1: all input-only work
  k_combo1<<<NB_PREP + 400 + 240, 256, 0, stream>>>(
      Wlogit, q_seq, Wq_lin, f_out, Wqr, Wkr, logits, v_out,
      Wn, Wr, br, Wa, ba, Wptr, bptr,
      Wlbf, qbf, Wqlb, fb, vb, qwb, WqrT, WkrT,
      vn, vn2, attn, remv, addp, pgen);

  // L2: vocab 600 + u/kh GEMMs + vWqr GEMM + attnw
  k_combo2<<<600 + 44 + 52 + 960, 256, 0, stream>>>(
      qbf, Wlbf, blogit, out, qwb, Wqlb, u, fb, WkrT, bkr, khf,
      vb, WqrT, vWqr, attn, vn2, remv, ra, ctxn);

  // L3: vubeta + bilinear M + vocab 600
  k_combo3<<<80 + 128 + 600, 256, 0, stream>>>(
      u, v_out, attn, ra, addp, ctxn, vn, bn, gammaTt,
      vWqr, khf, bqr, M, qbf, Wlbf, blogit, out);

  // L4: vocab 800 + role (reads gamma·M directly; qh stage eliminated)
  k_rolep<<<800 + BT, 256, 0, stream>>>(M, gammaTt, pgen, out, qbf, Wlbf, blogit);
}

// Round 16
// 165.452 us; speedup vs baseline: 1.0483x; 1.0483x over previous
//
#include <hip/hip_runtime.h>
#include <math.h>

// Problem constants
constexpr int B = 16, S = 100, T = 60, D = 512, H = 8, V = 32000, R = 20;
constexpr int DK = 64, WIN = 20;
constexpr int VR = V + R;        // 32020
constexpr int BT = B * T;        // 960
constexpr int MP = 1024;         // padded GEMM M
constexpr int FP = 384;          // padded B*R rows for kh GEMM
constexpr int VBP = 1664;        // padded B*S rows for vWqr GEMM (13*128)

typedef unsigned short u16;
typedef __attribute__((ext_vector_type(8))) short bf16x8;
typedef __attribute__((ext_vector_type(4))) float f32x4;

__device__ __forceinline__ float wred_sum(float v) {
#pragma unroll
  for (int st = 32; st > 0; st >>= 1) v += __shfl_xor(v, st, 64);
  return v;
}
__device__ __forceinline__ float wred_max(float v) {
#pragma unroll
  for (int st = 32; st > 0; st >>= 1) v = fmaxf(v, __shfl_xor(v, st, 64));
  return v;
}
__device__ __forceinline__ float sigmoidf_(float x) { return 1.f / (1.f + expf(-x)); }
__device__ __forceinline__ u16 f2bf(float x) {
  unsigned u = __float_as_uint(x);
  return (u16)((u + 0x7fffu + ((u >> 16) & 1u)) >> 16);
}
__device__ __forceinline__ void gload_lds16(const u16* g, u16* l) {
  __builtin_amdgcn_global_load_lds((const __attribute__((address_space(1))) void*)g,
                                   (__attribute__((address_space(3))) void*)l, 16, 0, 0);
}

// ================= bodies =================

__device__ __forceinline__ void vn_body(int row, int l, const float* __restrict__ v,
                                        const float* __restrict__ Wn,
                                        float* __restrict__ vn, float* __restrict__ vn2) {
  const float* vr = v + (size_t)row * D + l * 8;
  float p0 = 0.f, p1 = 0.f;
#pragma unroll
  for (int i = 0; i < 8; i++) {
    float x = vr[i];
    p0 = fmaf(x, Wn[l * 8 + i], p0);
    p1 = fmaf(x, Wn[D + l * 8 + i], p1);
  }
  p0 = wred_sum(p0); p1 = wred_sum(p1);
  if (l == 0) { vn[row] = p0; vn2[row] = p1; }
}

__device__ __forceinline__ void attnscal_body(int row, int l,
    const float* __restrict__ logits, const float* __restrict__ q,
    const float* __restrict__ Wr, const float* __restrict__ br,
    const float* __restrict__ Wa, const float* __restrict__ ba,
    const float* __restrict__ Wptr, const float* __restrict__ bptr,
    float* __restrict__ attn_g, float* __restrict__ remv,
    float* __restrict__ addp, float* __restrict__ pgen) {
  const float* src = logits + (size_t)row * S;
  float a = src[l];
  float b2 = (l + 64 < S) ? src[l + 64] : -INFINITY;
  float m = wred_max(fmaxf(a, b2));
  float ea = expf(a - m), eb = (l + 64 < S) ? expf(b2 - m) : 0.f;
  float inv = 1.f / wred_sum(ea + eb);
  attn_g[(size_t)row * S + l] = ea * inv;
  if (l + 64 < S) attn_g[(size_t)row * S + l + 64] = eb * inv;

  const float* qr = q + (size_t)row * D + l * 8;
  float pr = 0.f, pa = 0.f, pp = 0.f;
#pragma unroll
  for (int i = 0; i < 8; i++) {
    float x = qr[i];
    pr = fmaf(x, Wr[l * 8 + i], pr);
    pa = fmaf(x, Wa[l * 8 + i], pa);
    pp = fmaf(x, Wptr[l * 8 + i], pp);
  }
#pragma unroll
  for (int st = 32; st > 0; st >>= 1) {
    pr += __shfl_xor(pr, st, 64);
    pa += __shfl_xor(pa, st, 64);
    pp += __shfl_xor(pp, st, 64);
  }
  if (l == 0) {
    remv[row] = sigmoidf_(pr + br[0]);
    addp[row] = sigmoidf_(pa + ba[0]);
    pgen[row] = sigmoidf_(pp + bptr[0]);
  }
}

__device__ __forceinline__ void attnw_body(int row, int tid, float* red,
    const float* __restrict__ attn, const float* __restrict__ vn2,
    const float* __restrict__ remv, float* __restrict__ ra, float* __restrict__ ctxn) {
  int b = row / T, t = row % T;
  int L = min(t + 1, WIN);
  if (tid < 128) {
    float dnm = 0.f;
    for (int j = 0; j < L; j++) dnm += expf((float)(WIN - j) / 20.f);
    float p = 0.f;
    if (tid < S) {
      float aw = 0.f;
      for (int j = 0; j < L; j++)
        aw = fmaf(expf((float)(WIN - j) / 20.f) / dnm, attn[(size_t)(row - j) * S + tid], aw);
      ra[(size_t)row * S + tid] = remv[row] * aw;
      p = aw * vn2[b * S + tid];
    }
    red[tid] = p;
  }
  __syncthreads();
  if (tid < 64) {
    float v2 = red[tid] + red[tid + 64];
    v2 = wred_sum(v2);
    if (tid == 0) ctxn[row] = v2;
  }
}

// ---- prep (conversions incl Wlogit & v->bf16, qw window, weight transposes) ----
constexpr int NW = V * D / 4;                      // 4,096,000
constexpr int NQ = MP * D / 4;                     // 131,072
constexpr int NWQ = D * D / 4;                     // 65,536
constexpr int NF = FP * D / 4;                     // 49,152
constexpr int NVB = VBP * D / 4;                   // 212,992
constexpr int NB_CVT = (NW + NQ + NWQ + NF + NVB) / 256;  // 17792 exact
constexpr int NB_QWB = MP;
constexpr int NB_PREP = NB_CVT + NB_QWB + 128;     // 18944
__device__ __forceinline__ void prep_body(int blk, int tid, float (*tile)[65],
    const float* __restrict__ Wlogit, const float* __restrict__ q,
    const float* __restrict__ Wq, const float* __restrict__ f, const float* __restrict__ v,
    const float* __restrict__ Wqr, const float* __restrict__ Wkr,
    u16* __restrict__ Wlbf, u16* __restrict__ qbf,
    u16* __restrict__ Wqlb, u16* __restrict__ fb, u16* __restrict__ vb,
    u16* __restrict__ qwb, u16* __restrict__ WqrT, u16* __restrict__ WkrT) {
  if (blk < NB_CVT) {
    int idx = blk * 256 + tid;
    if (idx < NW) {
      float4 x = reinterpret_cast<const float4*>(Wlogit)[idx];
      ushort4 o = {f2bf(x.x), f2bf(x.y), f2bf(x.z), f2bf(x.w)};
      reinterpret_cast<ushort4*>(Wlbf)[idx] = o;
    } else if (idx < NW + NQ) {
      int j = idx - NW;
      int row = (j * 4) / D;
      ushort4 o = {0, 0, 0, 0};
      if (row < BT) {
        float4 x = reinterpret_cast<const float4*>(q)[j];
        o = {f2bf(x.x), f2bf(x.y), f2bf(x.z), f2bf(x.w)};
      }
      reinterpret_cast<ushort4*>(qbf)[j] = o;
    } else if (idx < NW + NQ + NWQ) {
      int j = idx - NW - NQ;
      float4 x = reinterpret_cast<const float4*>(Wq)[j];
      ushort4 o = {f2bf(x.x), f2bf(x.y), f2bf(x.z), f2bf(x.w)};
      reinterpret_cast<ushort4*>(Wqlb)[j] = o;
    } else if (idx < NW + NQ + NWQ + NF) {
      int j = idx - NW - NQ - NWQ;
      int row = (j * 4) / D;
      ushort4 o = {0, 0, 0, 0};
      if (row < B * R) {
        float4 x = reinterpret_cast<const float4*>(f)[j];
        o = {f2bf(x.x), f2bf(x.y), f2bf(x.z), f2bf(x.w)};
      }
      reinterpret_cast<ushort4*>(fb)[j] = o;
    } else {
      int j = idx - NW - NQ - NWQ - NF;            // 0 .. NVB-1
      int row = (j * 4) / D;
      ushort4 o = {0, 0, 0, 0};
      if (row < B * S) {
        float4 x = reinterpret_cast<const float4*>(v)[j];
        o = {f2bf(x.x), f2bf(x.y), f2bf(x.z), f2bf(x.w)};
      }
      reinterpret_cast<ushort4*>(vb)[j] = o;
    }
  } else if (blk < NB_CVT + NB_QWB) {
    int row = blk - NB_CVT;
    if (row >= BT) {
      qwb[(size_t)row * D + tid] = 0; qwb[(size_t)row * D + tid + 256] = 0;
      return;
    }
    int t = row % T, L = min(t + 1, WIN);
    float dnm = 0.f;
    for (int j = 0; j < L; j++) dnm += expf((float)(WIN - j) / 20.f);
    float a0 = 0.f, a1 = 0.f;
    for (int j = 0; j < L; j++) {
      float wj = expf((float)(WIN - j) / 20.f) / dnm;
      a0 = fmaf(wj, q[(size_t)(row - j) * D + tid], a0);
      a1 = fmaf(wj, q[(size_t)(row - j) * D + tid + 256], a1);
    }
    qwb[(size_t)row * D + tid] = f2bf(a0);
    qwb[(size_t)row * D + tid + 256] = f2bf(a1);
  } else {
    int qt = blk - NB_CVT - NB_QWB;                // 0..127
    const float* src = (qt < 64) ? Wqr : Wkr;
    u16* dst = (qt < 64) ? WqrT : WkrT;
    int q64 = qt & 63;
    int bx = q64 % 8, by = q64 / 8;
#pragma unroll
    for (int i = 0; i < 16; i++) {
      int e = i * 256 + tid, r = e >> 6, c = e & 63;
      tile[r][c] = src[(size_t)(by * 64 + r) * D + bx * 64 + c];
    }
    __syncthreads();
#pragma unroll
    for (int i = 0; i < 16; i++) {
      int e = i * 256 + tid, r = e >> 6, c = e & 63;
      dst[(size_t)(bx * 64 + r) * D + by * 64 + c] = f2bf(tile[c][r]);
    }
  }
}

__device__ __forceinline__ void gemm512_body(const u16* __restrict__ A, const u16* __restrict__ Bw,
                                             const float* __restrict__ bias, float* __restrict__ outp,
                                             int mlimit, int mt, int nt, int tid, u16* ldsbuf) {
  u16* As = ldsbuf;
  u16* Bs = ldsbuf + 128 * 64;
  int m0 = mt * 128, n0 = nt * 128;
  int l = tid & 63;
  int w = tid >> 6, wm = w >> 1, wn = w & 1;
  f32x4 acc[4][4];
#pragma unroll
  for (int mb = 0; mb < 4; mb++)
#pragma unroll
    for (int nb = 0; nb < 4; nb++) acc[mb][nb] = (f32x4){0.f, 0.f, 0.f, 0.f};

  for (int k0 = 0; k0 < D; k0 += 64) {
#pragma unroll
    for (int i = 0; i < 4; i++) {
      int chunk = i * 256 + tid;
      int row = chunk >> 3, kc = chunk & 7;
      int kcs = kc ^ (row & 7);
      gload_lds16(A + (size_t)(m0 + row) * D + k0 + kcs * 8, As + chunk * 8);
      gload_lds16(Bw + (size_t)(n0 + row) * D + k0 + kcs * 8, Bs + chunk * 8);
    }
    __syncthreads();
#pragma unroll
    for (int kk = 0; kk < 2; kk++) {
      bf16x8 af[4], bfr[4];
#pragma unroll
      for (int mb = 0; mb < 4; mb++) {
        int row = wm * 64 + mb * 16 + (l & 15);
        int kc0 = kk * 4 + (l >> 4);
        af[mb] = *(const bf16x8*)(As + row * 64 + ((kc0 ^ (row & 7)) << 3));
      }
#pragma unroll
      for (int nb = 0; nb < 4; nb++) {
        int row = wn * 64 + nb * 16 + (l & 15);
        int kc0 = kk * 4 + (l >> 4);
        bfr[nb] = *(const bf16x8*)(Bs + row * 64 + ((kc0 ^ (row & 7)) << 3));
      }
#pragma unroll
      for (int mb = 0; mb < 4; mb++)
#pragma unroll
        for (int nb = 0; nb < 4; nb++)
          acc[mb][nb] = __builtin_amdgcn_mfma_f32_16x16x32_bf16(af[mb], bfr[nb], acc[mb][nb], 0, 0, 0);
    }
    __syncthreads();
  }

  float* ch = (float*)ldsbuf;
#pragma unroll
  for (int c = 0; c < 4; c++) {
    if (wm == (c >> 1)) {
#pragma unroll
      for (int nb = 0; nb < 4; nb++) {
        int col = wn * 64 + nb * 16 + (l & 15);
        float bl = bias ? bias[n0 + col] : 0.f;
#pragma unroll
        for (int mbi = 0; mbi < 2; mbi++) {
          int mb = (c & 1) * 2 + mbi;
#pragma unroll
          for (int q2 = 0; q2 < 4; q2++) {
            int row_local = mb * 16 + (l >> 4) * 4 + q2 - (c & 1) * 32;
            ch[row_local * 132 + col] = acc[mb][nb][q2] + bl;
          }
        }
      }
    }
    __syncthreads();
#pragma unroll
    for (int p = 0; p < 4; p++) {
      int r = p * 8 + (tid >> 5);
      int m = m0 + c * 32 + r;
      if (m < mlimit) {
        int seg = tid & 31;
        *(float4*)(outp + (size_t)m * D + n0 + seg * 4) =
            *(const float4*)(ch + r * 132 + seg * 4);
      }
    }
    __syncthreads();
  }
}

__device__ __forceinline__ void vocab_body(int bid, int tid, u16* ldsbuf,
    const u16* __restrict__ A, const u16* __restrict__ Bw,
    const float* __restrict__ blog, float* __restrict__ out) {
  u16* As = ldsbuf;
  u16* Bs = ldsbuf + 128 * 64;
  int swz = (bid & 7) * 250 + (bid >> 3);          // bijective on [0,2000)
  int m0 = (swz & 7) * 128, n0 = (swz >> 3) * 128;
  int l = tid & 63;
  int w = tid >> 6, wm = w >> 1, wn = w & 1;

  f32x4 acc[4][4];
#pragma unroll
  for (int mb = 0; mb < 4; mb++)
#pragma unroll
    for (int nb = 0; nb < 4; nb++) acc[mb][nb] = (f32x4){0.f, 0.f, 0.f, 0.f};

  for (int k0 = 0; k0 < D; k0 += 64) {
#pragma unroll
    for (int i = 0; i < 4; i++) {
      int chunk = i * 256 + tid;
      int row = chunk >> 3, kc = chunk & 7;
      int kcs = kc ^ (row & 7);
      gload_lds16(A + (size_t)(m0 + row) * D + k0 + kcs * 8, As + chunk * 8);
      gload_lds16(Bw + (size_t)(n0 + row) * D + k0 + kcs * 8, Bs + chunk * 8);
    }
    __syncthreads();
#pragma unroll
    for (int kk = 0; kk < 2; kk++) {
      bf16x8 af[4], bfr[4];
#pragma unroll
      for (int mb = 0; mb < 4; mb++) {
        int row = wm * 64 + mb * 16 + (l & 15);
        int kc0 = kk * 4 + (l >> 4);
        af[mb] = *(const bf16x8*)(As + row * 64 + ((kc0 ^ (row & 7)) << 3));
      }
#pragma unroll
      for (int nb = 0; nb < 4; nb++) {
        int row = wn * 64 + nb * 16 + (l & 15);
        int kc0 = kk * 4 + (l >> 4);
        bfr[nb] = *(const bf16x8*)(Bs + row * 64 + ((kc0 ^ (row & 7)) << 3));
      }
#pragma unroll
      for (int mb = 0; mb < 4; mb++)
#pragma unroll
        for (int nb = 0; nb < 4; nb++)
          acc[mb][nb] = __builtin_amdgcn_mfma_f32_16x16x32_bf16(af[mb], bfr[nb], acc[mb][nb], 0, 0, 0);
    }
    __syncthreads();
  }

  float* ch = (float*)ldsbuf;
#pragma unroll
  for (int c = 0; c < 4; c++) {
    if (wm == (c >> 1)) {
#pragma unroll
      for (int nb = 0; nb < 4; nb++) {
        int col = wn * 64 + nb * 16 + (l & 15);
        float bl = blog[n0 + col];
#pragma unroll
        for (int mbi = 0; mbi < 2; mbi++) {
          int mb = (c & 1) * 2 + mbi;
#pragma unroll
          for (int q2 = 0; q2 < 4; q2++) {
            int row_local = mb * 16 + (l >> 4) * 4 + q2 - (c & 1) * 32;
            ch[row_local * 132 + col] = acc[mb][nb][q2] + bl;
          }
        }
      }
    }
    __syncthreads();
#pragma unroll
    for (int p = 0; p < 4; p++) {
      int r = p * 8 + (tid >> 5);
      int m = m0 + c * 32 + r;
      if (m < BT) {
        int seg = tid & 31;
        *(float4*)(out + (size_t)m * VR + n0 + seg * 4) =
            *(const float4*)(ch + r * 132 + seg * 4);
      }
    }
    __syncthreads();
  }
}

// ---- M[b,h,r,s] = sum_dk vWqr[b,s,h*64+dk]*khf[b,r,h*64+dk]; slot s=100 holds bias term ----
// smem: kh 1280 + vW 6400 + bq 64 = 7744 floats (31 KB)
__device__ __forceinline__ void mrole_body(int bh, int tid, float* sm,
    const float* __restrict__ vWqr, const float* __restrict__ khf,
    const float* __restrict__ bqr, float* __restrict__ M) {
  int b = bh >> 3, h = bh & 7;
  float* kh_s = sm;              // [20][64]
  float* vW_s = sm + 1280;       // [100][64]
  float* bq_s = sm + 7680;       // [64]
#pragma unroll
  for (int ii = 0; ii < 2; ii++) {
    int i = ii * 256 + tid;
    if (i < 320) {                                 // 20*16 float4
      int r = i >> 4, c4 = (i & 15) * 4;
      *(float4*)&kh_s[r * 64 + c4] =
          *(const float4*)&khf[(size_t)(b * R + r) * D + h * 64 + c4];
    }
  }
#pragma unroll
  for (int ii = 0; ii < 7; ii++) {
    int i = ii * 256 + tid;
    if (i < 1600) {                                // 100*16 float4
      int s = i >> 4, c4 = (i & 15) * 4;
      *(float4*)&vW_s[s * 64 + c4] =
          *(const float4*)&vWqr[(size_t)(b * S + s) * D + h * 64 + c4];
    }
  }
  if (tid < 64) bq_s[tid] = bqr[h * 64 + tid];
  __syncthreads();
  for (int p = tid; p < R * 104; p += 256) {
    int r = p / 104, sc = p % 104;
    if (sc > 100) continue;
    const float* kp = kh_s + r * 64;
    const float* xp = (sc < 100) ? (vW_s + sc * 64) : bq_s;
    float acc = 0.f;
#pragma unroll
    for (int e = 0; e < 64; e += 4) {
      float4 x = *(const float4*)&xp[e];
      float4 k = *(const float4*)&kp[e];
      acc = fmaf(x.x, k.x, fmaf(x.y, k.y, fmaf(x.z, k.z, fmaf(x.w, k.w, acc))));
    }
    M[(size_t)(bh * R + r) * 104 + sc] = acc;
  }
}

// ---- vubeta: 64-wide K chunks, vectorized unrolled float4 staging, 31.9 KB LDS ----
// smem floats: u_s[60][68] @0 (4080), v_s[20][68] @4080 (1360), aw @5440 (1200),
// ra @6640 (1200), ap @7840 (60), cx @7900 (60), vns @7960 (20) = 7980 total.
// vu aliases u_s (free after dot phase); gamma written direct to global.
__device__ __forceinline__ void vubeta_body(int bq, int tid, float* sm,
    const float* __restrict__ u, const float* __restrict__ v,
    const float* __restrict__ attn, const float* __restrict__ ra,
    const float* __restrict__ addp, const float* __restrict__ ctxn,
    const float* __restrict__ vn, const float* __restrict__ bn,
    float* __restrict__ gammaTt) {
  int b = bq / 5, sc = bq % 5;
  int tq = tid >> 2, sg = tid & 3;
  float* u_s  = sm;
  float* v_s  = sm + 4080;
  float* aw_s = sm + 5440;
  float* ra_s = sm + 6640;
  float* ap_s = sm + 7840;
  float* cx_s = sm + 7900;
  float* vns_s= sm + 7960;
#pragma unroll
  for (int ii = 0; ii < 5; ii++) {
    int i = ii * 256 + tid;
    if (i < T * 20) {
      int t = i / 20, sl = i % 20;
      size_t base = ((size_t)b * T + t) * S + sc * 20 + sl;
      aw_s[t * 20 + sl] = attn[base];
      ra_s[t * 20 + sl] = ra[base];
    }
  }
  if (tid < T) { ap_s[tid] = addp[b * T + tid]; cx_s[tid] = ctxn[b * T + tid]; }
  if (tid >= 64 && tid < 84) vns_s[tid - 64] = vn[b * S + sc * 20 + tid - 64];

  float acc[5] = {0, 0, 0, 0, 0};
  for (int kc = 0; kc < 8; kc++) {                 // 64-wide K chunks
    // u: 60 rows x 16 float4 = 960, 4 unrolled independent loads/thread
#pragma unroll
    for (int ii = 0; ii < 4; ii++) {
      int i = ii * 256 + tid;
      if (i < 60 * 16) {
        int r = i >> 4, c = (i & 15) * 4;
        *(float4*)&u_s[r * 68 + c] =
            *(const float4*)&u[((size_t)b * T + r) * D + kc * 64 + c];
      }
    }
    // v: 20 rows x 16 float4 = 320, 2 unrolled loads/thread
#pragma unroll
    for (int ii = 0; ii < 2; ii++) {
      int i = ii * 256 + tid;
      if (i < 20 * 16) {
        int r = i >> 4, c = (i & 15) * 4;
        *(float4*)&v_s[r * 68 + c] =
            *(const float4*)&v[((size_t)b * S + sc * 20 + r) * D + kc * 64 + c];
      }
    }
    __syncthreads();
    if (tq < 60) {
#pragma unroll
      for (int e0 = 0; e0 < 64; e0 += 4) {
        float4 uu = *(const float4*)&u_s[tq * 68 + e0];
#pragma unroll
        for (int m = 0; m < 5; m++) {
          float4 vv = *(const float4*)&v_s[(sg * 5 + m) * 68 + e0];
          acc[m] = fmaf(uu.x, vv.x, acc[m]);
          acc[m] = fmaf(uu.y, vv.y, acc[m]);
          acc[m] = fmaf(uu.z, vv.z, acc[m]);
          acc[m] = fmaf(uu.w, vv.w, acc[m]);
        }
      }
    }
    __syncthreads();
  }
  // vu aliases the (now dead) u_s region — barrier above guarantees reads done
  float* vu_s = u_s;
  if (tq < 60) {
#pragma unroll
    for (int m = 0; m < 5; m++) vu_s[tq * 20 + sg * 5 + m] = acc[m];
  }
  __syncthreads();
  // fused add_state + beta chains; gamma written straight to global (t-major)
  if (tid < 20) {
    int s = sc * 20 + tid;
    float dec = (s < 50) ? 1.f - (float)(s + 1) / 50.f : 0.f;
    float a = dec, beta = dec;
    float vns = vns_s[tid], bnv = bn[0];
    for (int t = 0; t < T; t++) {
      float g = ap_s[t] * sigmoidf_(vns + cx_s[t] + bnv);
      float wv = (1.f - a) * g;
      a += wv;
      gammaTt[((size_t)b * T + t) * S + s] = aw_s[t * 20 + tid] * beta;  // PRE-update beta
      beta = beta * (1.f - ra_s[t * 20 + tid] * sigmoidf_(beta * vu_s[t * 20 + tid])) + wv;
    }
  }
}

// ---- role from gamma·M (qh eliminated) ----
__device__ __forceinline__ void role_body(int row, int tid, float* sm,
    const float* __restrict__ M, const float* __restrict__ gammaTt,
    const float* __restrict__ pgen, float* __restrict__ out) {
  int b = row / T;
  float* gs = sm;                // [100]
  float* sc = sm + 104;          // [160]
  float* pr = sm + 264;          // [160]
  if (tid < S) gs[tid] = gammaTt[(size_t)row * S + tid];
  __syncthreads();
  if (tid < H * R) {
    int h = tid / R, r = tid % R;
    const float* mp = M + (size_t)((b * H + h) * R + r) * 104;
    float acc = mp[100];                           // folded bqr·kh bias term
    for (int s = 0; s < S; s++) acc = fmaf(gs[s], mp[s], acc);
    sc[tid] = acc * 0.125f;                        // 1/sqrt(64)
  }
  __syncthreads();
  if (tid < H) {
    float m = -INFINITY;
    for (int r = 0; r < R; r++) m = fmaxf(m, sc[tid * R + r]);
    float ssum = 0.f;
    for (int r = 0; r < R; r++) { float e = expf(sc[tid * R + r] - m); pr[tid * R + r] = e; ssum += e; }
    float inv = 1.f / ssum;
    for (int r = 0; r < R; r++) pr[tid * R + r] *= inv;
  }
  __syncthreads();
  if (tid < R) {
    float acc = 0.f;
#pragma unroll
    for (int h = 0; h < H; h++) acc += pr[h * R + tid];
    out[(size_t)row * VR + V + tid] = acc * (1.f / H) * pgen[row];
  }
}

// ================= dispatch kernels (all 32 KB static LDS -> 5 blocks/CU) =================

// L1: prep (incl Wlogit/v cvt) + vn + attnscal — all input-only
__global__ __launch_bounds__(256) void k_combo1(
    const float* Wlogit, const float* q, const float* Wq, const float* f,
    const float* Wqr, const float* Wkr, const float* logits, const float* v,
    const float* Wn, const float* Wr, const float* br, const float* Wa, const float* ba,
    const float* Wptr, const float* bptr,
    u16* Wlbf, u16* qbf, u16* Wqlb, u16* fb, u16* vb, u16* qwb, u16* WqrT, u16* WkrT,
    float* vn, float* vn2, float* attn_g, float* remv, float* addp, float* pgen) {
  __shared__ float tile[64][65];
  int blk = blockIdx.x, tid = threadIdx.x;
  if (blk < NB_PREP) {
    prep_body(blk, tid, tile, Wlogit, q, Wq, f, v, Wqr, Wkr,
              Wlbf, qbf, Wqlb, fb, vb, qwb, WqrT, WkrT);
  } else if (blk < NB_PREP + 400) {
    int row = (blk - NB_PREP) * 4 + (tid >> 6);    // 1600 rows
    vn_body(row, tid & 63, v, Wn, vn, vn2);
  } else {
    int row = (blk - NB_PREP - 400) * 4 + (tid >> 6);  // 960 rows
    attnscal_body(row, tid & 63, logits, q, Wr, br, Wa, ba, Wptr, bptr,
                  attn_g, remv, addp, pgen);
  }
}

// L2: vocab [0,600) + dual gemm (44) + vWqr gemm (52) + attnw (960)
__global__ __launch_bounds__(256) void k_combo2(
    const u16* qbf, const u16* Wlbf, const float* blog, float* out,
    const u16* qwb, const u16* Wqlb, float* u,
    const u16* fb, const u16* WkrT, const float* bkr, float* khf,
    const u16* vb, const u16* WqrT, float* vWqr,
    const float* attn, const float* vn2, const float* remv, float* ra, float* ctxn) {
  __shared__ u16 lds[2 * 128 * 64];
  int blk = blockIdx.x, tid = threadIdx.x;
  if (blk < 600) {
    vocab_body(blk, tid, lds, qbf, Wlbf, blog, out);
  } else if (blk < 644) {
    int z = blk - 600, xx = z % 11, yy = z / 11;
    if (xx < 8) gemm512_body(qwb, Wqlb, nullptr, u, BT, xx, yy, tid, lds);
    else        gemm512_body(fb, WkrT, bkr, khf, B * R, xx - 8, yy, tid, lds);
  } else if (blk < 696) {
    int z = blk - 644;                             // 52 blocks: 13 x 4
    gemm512_body(vb, WqrT, nullptr, vWqr, B * S, z % 13, z / 13, tid, lds);
  } else {
    attnw_body(blk - 696, tid, (float*)lds, attn, vn2, remv, ra, ctxn);
  }
}

// L3: vubeta (80) + M-compute (128) + vocab [600,1300) — all 32 KB now
__global__ __launch_bounds__(256) void k_combo3(
    const float* u, const float* v, const float* attn, const float* ra,
    const float* addp, const float* ctxn, const float* vn, const float* bn,
    float* gammaTt,
    const float* vWqr, const float* khf, const float* bqr, float* M,
    const u16* qbf, const u16* Wlbf, const float* blog, float* out) {
  __shared__ u16 lds[2 * 128 * 64];                // 32 KB uniform
  int blk = blockIdx.x, tid = threadIdx.x;
  if (blk < 80)       vubeta_body(blk, tid, (float*)lds, u, v, attn, ra, addp, ctxn, vn, bn, gammaTt);
  else if (blk < 208) mrole_body(blk - 80, tid, (float*)lds, vWqr, khf, bqr, M);
  else                vocab_body(600 + blk - 208, tid, lds, qbf, Wlbf, blog, out);
}

// L4: vocab [1300,2000) + role (960)
__global__ __launch_bounds__(256) void k_rolep(
    const float* M, const float* gammaTt, const float* pgen, float* out,
    const u16* qbf, const u16* Wlbf, const float* blog) {
  __shared__ u16 lds[2 * 128 * 64];
  int blk = blockIdx.x, tid = threadIdx.x;
  if (blk < 700) vocab_body(1300 + blk, tid, lds, qbf, Wlbf, blog, out);
  else           role_body(blk - 700, tid, (float*)lds, M, gammaTt, pgen, out);
}

extern "C" void kernel_launch(void* const* d_in, const int* in_sizes, int n_in,
                              void* d_out, int out_size, void* d_ws, size_t ws_size,
                              hipStream_t stream) {
  const float* v_out  = (const float*)d_in[0];
  const float* f_out  = (const float*)d_in[1];
  const float* q_seq  = (const float*)d_in[2];
  const float* logits = (const float*)d_in[3];
  const float* Wr     = (const float*)d_in[4];
  const float* br     = (const float*)d_in[5];
  const float* Wa     = (const float*)d_in[6];
  const float* ba     = (const float*)d_in[7];
  const float* Wq_lin = (const float*)d_in[8];
  const float* Wn     = (const float*)d_in[9];
  const float* bn     = (const float*)d_in[10];
  const float* Wlogit = (const float*)d_in[11];
  const float* blogit = (const float*)d_in[12];
  const float* Wptr   = (const float*)d_in[13];
  const float* bptr   = (const float*)d_in[14];
  const float* Wqr    = (const float*)d_in[15];
  const float* bqr    = (const float*)d_in[16];
  const float* Wkr    = (const float*)d_in[17];
  const float* bkr    = (const float*)d_in[18];
  float* out = (float*)d_out;
  float* ws  = (float*)d_ws;

  float* attn   = ws;                                  // BT*S
  float* ra     = attn   + (size_t)BT * S;             // BT*S
  float* u      = ra     + (size_t)BT * S;             // BT*D
  float* pgen   = u      + (size_t)BT * D;             // BT
  float* remv   = pgen   + BT;                         // BT
  float* addp   = remv   + BT;                         // BT
  float* ctxn   = addp   + BT;                         // BT
  float* vn     = ctxn   + BT;                         // B*S
  float* vn2    = vn     + B * S;                      // B*S
  float* khf    = vn2    + B * S;                      // B*R*D
  float* gammaTt= khf    + (size_t)B * R * D;          // BT*S
  float* M      = gammaTt+ (size_t)BT * S;             // B*H*R*104
  float* vWqr   = M      + (size_t)B * H * R * 104;    // B*S*D
  u16*   qwb    = (u16*)(vWqr + (size_t)B * S * D);    // MP*D
  u16*   vb     = qwb  + (size_t)MP * D;               // VBP*D
  u16*   fb     = vb   + (size_t)VBP * D;              // FP*D
  u16*   Wqlb   = fb   + (size_t)FP * D;               // D*D
  u16*   WqrT   = Wqlb + (size_t)D * D;                // D*D
  u16*   WkrT   = WqrT + (size_t)D * D;                // D*D
  u16*   qbf    = WkrT + (size_t)D * D;                // MP*D
  u16*   Wlbf   = qbf  + (size_t)MP * D;               // V*D

  // L1: all input-only work
  k_combo1<<<NB_PREP + 400 + 240, 256, 0, stream>>>(
      Wlogit, q_seq, Wq_lin, f_out, Wqr, Wkr, logits, v_out,
      Wn, Wr, br, Wa, ba, Wptr, bptr,
      Wlbf, qbf, Wqlb, fb, vb, qwb, WqrT, WkrT,
      vn, vn2, attn, remv, addp, pgen);

  // L2: vocab 600 + u/kh GEMMs + vWqr GEMM + attnw
  k_combo2<<<600 + 44 + 52 + 960, 256, 0, stream>>>(
      qbf, Wlbf, blogit, out, qwb, Wqlb, u, fb, WkrT, bkr, khf,
      vb, WqrT, vWqr, attn, vn2, remv, ra, ctxn);

  // L3: vubeta + bilinear M + vocab 700 (uniform 32 KB LDS -> 5 blocks/CU)
  k_combo3<<<80 + 128 + 700, 256, 0, stream>>>(
      u, v_out, attn, ra, addp, ctxn, vn, bn, gammaTt,
      vWqr, khf, bqr, M, qbf, Wlbf, blogit, out);

  // L4: vocab 700 + role
  k_rolep<<<700 + BT, 256, 0, stream>>>(M, gammaTt, pgen, out, qbf, Wlbf, blogit);
}